// Round 8
// baseline (602.376 us; speedup 1.0000x reference)
//
#include <hip/hip_runtime.h>
#include <math.h>

#define NU_F 0.0031830988618379067f

typedef _Float16 f16x8 __attribute__((ext_vector_type(8)));
typedef float    f32x4 __attribute__((ext_vector_type(4)));

// tanh(z) = 1 - 2/(exp2(z*2log2e)+1); 5 VALU (2 transcendental)
__device__ __forceinline__ float fast_tanh(float z) {
    float e = __builtin_amdgcn_exp2f(2.885390082f * z);
    float r = __builtin_amdgcn_rcpf(e + 1.0f);
    return fmaf(-2.0f, r, 1.0f);
}

// pack two f32 -> f16x2 in one u32 (v_cvt_pkrtz_f32_f16), low16 = a
__device__ __forceinline__ unsigned pkf16(float a, float b) {
    auto v = __builtin_amdgcn_cvt_pkrtz(a, b);   // __fp16 ext_vector(2)
    return __builtin_bit_cast(unsigned, v);
}

// ---------------------------------------------------------------------------
// Prep: W_hid fp32 [7][128(k)][128(c)] -> f16 hi/lo B-fragments, fragment-
// major (each wave-load = one coalesced 1 KiB block):
//   fid = ((l*8 + nt)*2 + hl)*4 + ks ; element = fid*512 + lane*8 + jj
//   k = ks*32 + q*8 + jj, lane = q*16 + nn
//   channel map: nt = ((c>>5)<<1)|(c&1), nn = (c>>1)&15  ->  c = wv*32+nn*2+j
// hi = RNE f16 (C cast); lo = residual (|lo| <= 2^-11 |w|).
// ---------------------------------------------------------------------------
__global__ void prep_wfrag(const float* __restrict__ Whid, _Float16* __restrict__ wcf)
{
    int t = blockIdx.x * 256 + threadIdx.x;   // 0 .. 114687
    const int l = t >> 14;
    const int r = t & 16383;
    const int k = r >> 7;
    const int c = r & 127;
    const float v = Whid[t];
    const _Float16 hi = (_Float16)v;
    const _Float16 lo = (_Float16)(v - (float)hi);
    const int ks = k >> 5, q = (k >> 3) & 3, jj = k & 7;
    const int nt = ((c >> 5) << 1) | (c & 1);
    const int nn = (c >> 1) & 15;
    const int lane = q * 16 + nn;
    const int base = (((l * 8 + nt) * 8) + ks) * 512 + lane * 8 + jj;  // hl=0
    wcf[base]        = hi;
    wcf[base + 2048] = lo;                                             // hl=1
}

#define HR 68
#define MFMA(A, B, C) __builtin_amdgcn_mfma_f32_16x16x32_f16((A), (B), (C), 0, 0, 0)

// ---------------------------------------------------------------------------
// Fused kernel, 256 thr = 4 waves, wave -> N-tiles {2wv, 2wv+1}.
// Blocks 0..8191: 16 deriv pts; M rows = s*16+p (jet states v,vx,vt,vxx).
// Blocks 8192..8319: 64 value-only pts; M rows = p.
// H: SINGLE f16 array (u32-packed channel pairs), 64 rows x 68 dwords.
// GEMM terms per product: ah*bh + ah*bl (A single f16, W f16 hi/lo).
// LDS ~18.8 KiB -> 8 blocks/CU.
// ---------------------------------------------------------------------------
__global__ __launch_bounds__(256, 8)
void pinn_fused(const float* __restrict__ xf,
                const float* __restrict__ x0,  const float* __restrict__ xbl,
                const float* __restrict__ xbr,
                const float* __restrict__ Win,  const float* __restrict__ bin,
                const float* __restrict__ bhid,
                const float* __restrict__ Wout, const float* __restrict__ bout,
                const _Float16* __restrict__ wcf,
                float* __restrict__ out)
{
    __shared__ unsigned Hh[64 * HR];
    __shared__ float xpt[128];
    __shared__ float pbuf[256];
    __shared__ float dots[64];

    const int tid  = threadIdx.x;
    const int lane = tid & 63;
    const int wv   = tid >> 6;
    const int lm   = lane & 15;
    const int lq   = lane >> 4;
    const int blk  = blockIdx.x;
    const bool isv = (blk >= 8192);

    if (!isv) {
        if (tid < 32) xpt[tid] = xf[blk * 32 + tid];
    } else {
        const int vb = blk - 8192;
        const float* src = (vb < 64) ? (x0 + vb * 128)
                         : (vb < 96) ? (xbl + (vb - 64) * 128)
                                     : (xbr + (vb - 96) * 128);
        if (tid < 128) xpt[tid] = src[tid];
    }
    __syncthreads();

    // ---- input layer: thread owns channel pair c0=2*(tid&63) ----
    const int cp = tid & 63;
    {
        const float2 w01 = *(const float2*)&Win[cp * 2];
        const float2 w11 = *(const float2*)&Win[128 + cp * 2];
        const float2 bb  = *(const float2*)&bin[cp * 2];
        if (!isv) {
            const int p0 = (tid >> 6) * 4;
            #pragma unroll
            for (int i = 0; i < 4; ++i) {
                const int p = p0 + i;
                const float x = xpt[2 * p], tt = xpt[2 * p + 1];
                const float za = fmaf(x, w01.x, fmaf(tt, w11.x, bb.x));
                const float zb = fmaf(x, w01.y, fmaf(tt, w11.y, bb.y));
                const float ya = fast_tanh(za), yb = fast_tanh(zb);
                const float da = 1.f - ya * ya, db = 1.f - yb * yb;
                Hh[(0 * 16 + p) * HR + cp] = pkf16(ya, yb);
                Hh[(1 * 16 + p) * HR + cp] = pkf16(da * w01.x, db * w01.y);
                Hh[(2 * 16 + p) * HR + cp] = pkf16(da * w11.x, db * w11.y);
                Hh[(3 * 16 + p) * HR + cp] =
                    pkf16(-2.f * ya * da * w01.x * w01.x,
                          -2.f * yb * db * w01.y * w01.y);
            }
        } else {
            const int p0 = (tid >> 6) * 16;
            #pragma unroll
            for (int i = 0; i < 16; ++i) {
                const int p = p0 + i;
                const float x = xpt[2 * p], tt = xpt[2 * p + 1];
                const float za = fmaf(x, w01.x, fmaf(tt, w11.x, bb.x));
                const float zb = fmaf(x, w01.y, fmaf(tt, w11.y, bb.y));
                Hh[p * HR + cp] = pkf16(fast_tanh(za), fast_tanh(zb));
            }
        }
    }
    __syncthreads();

    // B-fragment pointers (coalesced: lane*8 within each 512-elem fragment).
    const _Float16* pb0h = wcf + (wv * 2 + 0) * 4096 + lane * 8;
    const _Float16* pb0l = pb0h + 2048;
    const _Float16* pb1h = wcf + (wv * 2 + 1) * 4096 + lane * 8;
    const _Float16* pb1l = pb1h + 2048;
    const float2* bh2 = (const float2*)bhid + (wv * 16 + lm);
    const int wc = wv * 16 + lm;   // epilogue dword column

    if (!isv) {
        // ================= derivative path =================
        for (int l = 0; l < 7; ++l) {
            f32x4 acc[4][2];
            #pragma unroll
            for (int s = 0; s < 4; ++s)
                #pragma unroll
                for (int j = 0; j < 2; ++j) acc[s][j] = (f32x4){0.f, 0.f, 0.f, 0.f};

            #pragma unroll
            for (int ks = 0; ks < 4; ++ks) {
                const int ro = ks * 16 + lq * 4;
                const f16x8 ah0 = *(const f16x8*)&Hh[(0 * 16 + lm) * HR + ro];
                const f16x8 ah1 = *(const f16x8*)&Hh[(1 * 16 + lm) * HR + ro];
                const f16x8 ah2 = *(const f16x8*)&Hh[(2 * 16 + lm) * HR + ro];
                const f16x8 ah3 = *(const f16x8*)&Hh[(3 * 16 + lm) * HR + ro];
                const f16x8 bh0 = *(const f16x8*)(pb0h + ks * 512);
                const f16x8 bl0 = *(const f16x8*)(pb0l + ks * 512);
                const f16x8 bh1 = *(const f16x8*)(pb1h + ks * 512);
                const f16x8 bl1 = *(const f16x8*)(pb1l + ks * 512);
                acc[0][0] = MFMA(ah0, bh0, acc[0][0]);
                acc[0][0] = MFMA(ah0, bl0, acc[0][0]);
                acc[1][0] = MFMA(ah1, bh0, acc[1][0]);
                acc[1][0] = MFMA(ah1, bl0, acc[1][0]);
                acc[2][0] = MFMA(ah2, bh0, acc[2][0]);
                acc[2][0] = MFMA(ah2, bl0, acc[2][0]);
                acc[3][0] = MFMA(ah3, bh0, acc[3][0]);
                acc[3][0] = MFMA(ah3, bl0, acc[3][0]);
                acc[0][1] = MFMA(ah0, bh1, acc[0][1]);
                acc[0][1] = MFMA(ah0, bl1, acc[0][1]);
                acc[1][1] = MFMA(ah1, bh1, acc[1][1]);
                acc[1][1] = MFMA(ah1, bl1, acc[1][1]);
                acc[2][1] = MFMA(ah2, bh1, acc[2][1]);
                acc[2][1] = MFMA(ah2, bl1, acc[2][1]);
                acc[3][1] = MFMA(ah3, bh1, acc[3][1]);
                acc[3][1] = MFMA(ah3, bl1, acc[3][1]);
            }
            __syncthreads();

            const float2 bb = bh2[l * 64];
            #pragma unroll
            for (int r = 0; r < 4; ++r) {
                const int p = lq * 4 + r;
                float h[2][4];
                #pragma unroll
                for (int j = 0; j < 2; ++j) {
                    const float zv  = acc[0][j][r] + (j ? bb.y : bb.x);
                    const float zx  = acc[1][j][r];
                    const float zt  = acc[2][j][r];
                    const float zxx = acc[3][j][r];
                    const float y = fast_tanh(zv);
                    const float d = fmaf(-y, y, 1.f);
                    const float m = d * zx;            // = h1
                    h[j][0] = y;
                    h[j][1] = m;
                    h[j][2] = d * zt;
                    h[j][3] = fmaf(d, zxx, -2.f * (y * m) * zx);
                }
                Hh[(0 * 16 + p) * HR + wc] = pkf16(h[0][0], h[1][0]);
                Hh[(1 * 16 + p) * HR + wc] = pkf16(h[0][1], h[1][1]);
                Hh[(2 * 16 + p) * HR + wc] = pkf16(h[0][2], h[1][2]);
                Hh[(3 * 16 + p) * HR + wc] = pkf16(h[0][3], h[1][3]);
            }
            pb0h += 32768; pb0l += 32768; pb1h += 32768; pb1l += 32768;
            __syncthreads();
        }
    } else {
        // ================= value-only path =================
        for (int l = 0; l < 7; ++l) {
            f32x4 acc[4][2];
            #pragma unroll
            for (int mt = 0; mt < 4; ++mt)
                #pragma unroll
                for (int j = 0; j < 2; ++j) acc[mt][j] = (f32x4){0.f, 0.f, 0.f, 0.f};

            #pragma unroll
            for (int ks = 0; ks < 4; ++ks) {
                const int ro = ks * 16 + lq * 4;
                f16x8 ah[4];
                #pragma unroll
                for (int mt = 0; mt < 4; ++mt)
                    ah[mt] = *(const f16x8*)&Hh[(mt * 16 + lm) * HR + ro];
                const f16x8 bh0 = *(const f16x8*)(pb0h + ks * 512);
                const f16x8 bl0 = *(const f16x8*)(pb0l + ks * 512);
                const f16x8 bh1 = *(const f16x8*)(pb1h + ks * 512);
                const f16x8 bl1 = *(const f16x8*)(pb1l + ks * 512);
                #pragma unroll
                for (int mt = 0; mt < 4; ++mt) {
                    acc[mt][0] = MFMA(ah[mt], bh0, acc[mt][0]);
                    acc[mt][0] = MFMA(ah[mt], bl0, acc[mt][0]);
                    acc[mt][1] = MFMA(ah[mt], bh1, acc[mt][1]);
                    acc[mt][1] = MFMA(ah[mt], bl1, acc[mt][1]);
                }
            }
            __syncthreads();

            const float2 bb = bh2[l * 64];
            #pragma unroll
            for (int mt = 0; mt < 4; ++mt) {
                #pragma unroll
                for (int r = 0; r < 4; ++r) {
                    const int p = mt * 16 + lq * 4 + r;
                    Hh[p * HR + wc] = pkf16(fast_tanh(acc[mt][0][r] + bb.x),
                                            fast_tanh(acc[mt][1][r] + bb.y));
                }
            }
            pb0h += 32768; pb0l += 32768; pb1h += 32768; pb1l += 32768;
            __syncthreads();
        }
    }

    // ---- output layer: 64 dots of length 128 ----
    {
        const int st = tid & 63;
        const int ch = tid >> 6;      // 16 dwords (32 channels) per chunk
        const int cb = ch * 16;
        float part = 0.f;
        #pragma unroll
        for (int c8 = 0; c8 < 4; ++c8) {
            const f16x8 hv = *(const f16x8*)&Hh[st * HR + cb + c8 * 4];
            const float4 w1 = *(const float4*)&Wout[cb * 2 + c8 * 8];
            const float4 w2 = *(const float4*)&Wout[cb * 2 + c8 * 8 + 4];
            part = fmaf((float)hv[0], w1.x, part);
            part = fmaf((float)hv[1], w1.y, part);
            part = fmaf((float)hv[2], w1.z, part);
            part = fmaf((float)hv[3], w1.w, part);
            part = fmaf((float)hv[4], w2.x, part);
            part = fmaf((float)hv[5], w2.y, part);
            part = fmaf((float)hv[6], w2.z, part);
            part = fmaf((float)hv[7], w2.w, part);
        }
        pbuf[ch * 64 + st] = part;
    }
    __syncthreads();
    if (tid < 64)
        dots[tid] = pbuf[tid] + pbuf[64 + tid] + pbuf[128 + tid] + pbuf[192 + tid];
    __syncthreads();
    if (!isv) {
        if (tid < 16) {
            const float u = dots[tid] + bout[0];
            out[8192 + blk * 16 + tid] =
                dots[32 + tid] + u * dots[16 + tid] - NU_F * dots[48 + tid];
        }
    } else {
        if (tid < 64) out[(blk - 8192) * 64 + tid] = dots[tid] + bout[0];
    }
}

extern "C" void kernel_launch(void* const* d_in, const int* in_sizes, int n_in,
                              void* d_out, int out_size, void* d_ws, size_t ws_size,
                              hipStream_t stream) {
    (void)in_sizes; (void)n_in; (void)ws_size; (void)out_size;
    const float* xf   = (const float*)d_in[0];
    const float* x0   = (const float*)d_in[1];
    const float* xbl  = (const float*)d_in[2];
    const float* xbr  = (const float*)d_in[3];
    const float* Win  = (const float*)d_in[4];
    const float* bin  = (const float*)d_in[5];
    const float* Whid = (const float*)d_in[6];
    const float* bhid = (const float*)d_in[7];
    const float* Wout = (const float*)d_in[8];
    const float* bout = (const float*)d_in[9];
    float* out = (float*)d_out;

    _Float16* wcf = (_Float16*)d_ws;   // 7*128*128*2 f16 = 448 KiB

    hipLaunchKernelGGL(prep_wfrag, dim3(114688 / 256), dim3(256), 0, stream,
                       Whid, wcf);
    hipLaunchKernelGGL(pinn_fused, dim3(8192 + 128), dim3(256), 0, stream,
                       xf, x0, xbl, xbr, Win, bin, bhid, Wout, bout, wcf, out);
}

// Round 9
// 292.892 us; speedup vs baseline: 2.0567x; 2.0567x over previous
//
#include <hip/hip_runtime.h>
#include <math.h>

#define NU_F 0.0031830988618379067f

typedef _Float16 f16x8 __attribute__((ext_vector_type(8)));
typedef float    f32x4 __attribute__((ext_vector_type(4)));

// tanh(z) = 1 - 2/(exp2(z*2log2e)+1); 5 VALU (2 transcendental)
__device__ __forceinline__ float fast_tanh(float z) {
    float e = __builtin_amdgcn_exp2f(2.885390082f * z);
    float r = __builtin_amdgcn_rcpf(e + 1.0f);
    return fmaf(-2.0f, r, 1.0f);
}

// pack two f32 -> f16x2 in one u32 (v_cvt_pkrtz_f32_f16), low16 = a
__device__ __forceinline__ unsigned pkf16(float a, float b) {
    auto v = __builtin_amdgcn_cvt_pkrtz(a, b);   // __fp16 ext_vector(2)
    return __builtin_bit_cast(unsigned, v);
}

// ---------------------------------------------------------------------------
// Prep: W_hid fp32 [7][128(k)][128(c)] -> f16 hi/lo B-fragments, fragment-
// major (each wave-load = one coalesced 1 KiB block):
//   fid = ((l*8 + nt)*2 + hl)*4 + ks ; element = fid*512 + lane*8 + jj
//   k = ks*32 + q*8 + jj, lane = q*16 + nn
//   channel map: nt = ((c>>5)<<1)|(c&1), nn = (c>>1)&15  ->  c = wv*32+nn*2+j
// hi = RNE f16 (C cast); lo = residual (|lo| <= 2^-11 |w|).
// ---------------------------------------------------------------------------
__global__ void prep_wfrag(const float* __restrict__ Whid, _Float16* __restrict__ wcf)
{
    int t = blockIdx.x * 256 + threadIdx.x;   // 0 .. 114687
    const int l = t >> 14;
    const int r = t & 16383;
    const int k = r >> 7;
    const int c = r & 127;
    const float v = Whid[t];
    const _Float16 hi = (_Float16)v;
    const _Float16 lo = (_Float16)(v - (float)hi);
    const int ks = k >> 5, q = (k >> 3) & 3, jj = k & 7;
    const int nt = ((c >> 5) << 1) | (c & 1);
    const int nn = (c >> 1) & 15;
    const int lane = q * 16 + nn;
    const int base = (((l * 8 + nt) * 8) + ks) * 512 + lane * 8 + jj;  // hl=0
    wcf[base]        = hi;
    wcf[base + 2048] = lo;                                             // hl=1
}

#define HR 68
#define MFMA(A, B, C) __builtin_amdgcn_mfma_f32_16x16x32_f16((A), (B), (C), 0, 0, 0)

// ---------------------------------------------------------------------------
// Fused kernel, 256 thr = 4 waves, wave -> N-tiles {2wv, 2wv+1}.
// Blocks 0..8191: 16 deriv pts; M rows = s*16+p (jet states v,vx,vt,vxx).
// Blocks 8192..8319: 64 value-only pts; M rows = p.
// H: SINGLE f16 array (u32-packed channel pairs), 64 rows x 68 dwords.
// GEMM terms per product: ah*bh + ah*bl (A single f16, W f16 hi/lo).
// LDS ~18.8 KiB. __launch_bounds__(256,5): 102-reg budget -- (256,8)'s
// 64-reg cap caused a catastrophic scratch-spill storm (round 8: 1.3 GB
// HBM writes/dispatch, MfmaUtil 17%).
// ---------------------------------------------------------------------------
__global__ __launch_bounds__(256, 5)
void pinn_fused(const float* __restrict__ xf,
                const float* __restrict__ x0,  const float* __restrict__ xbl,
                const float* __restrict__ xbr,
                const float* __restrict__ Win,  const float* __restrict__ bin,
                const float* __restrict__ bhid,
                const float* __restrict__ Wout, const float* __restrict__ bout,
                const _Float16* __restrict__ wcf,
                float* __restrict__ out)
{
    __shared__ unsigned Hh[64 * HR];
    __shared__ float xpt[128];
    __shared__ float pbuf[256];
    __shared__ float dots[64];

    const int tid  = threadIdx.x;
    const int lane = tid & 63;
    const int wv   = tid >> 6;
    const int lm   = lane & 15;
    const int lq   = lane >> 4;
    const int blk  = blockIdx.x;
    const bool isv = (blk >= 8192);

    if (!isv) {
        if (tid < 32) xpt[tid] = xf[blk * 32 + tid];
    } else {
        const int vb = blk - 8192;
        const float* src = (vb < 64) ? (x0 + vb * 128)
                         : (vb < 96) ? (xbl + (vb - 64) * 128)
                                     : (xbr + (vb - 96) * 128);
        if (tid < 128) xpt[tid] = src[tid];
    }
    __syncthreads();

    // ---- input layer: thread owns channel pair c0=2*(tid&63) ----
    const int cp = tid & 63;
    {
        const float2 w01 = *(const float2*)&Win[cp * 2];
        const float2 w11 = *(const float2*)&Win[128 + cp * 2];
        const float2 bb  = *(const float2*)&bin[cp * 2];
        if (!isv) {
            const int p0 = (tid >> 6) * 4;
            #pragma unroll
            for (int i = 0; i < 4; ++i) {
                const int p = p0 + i;
                const float x = xpt[2 * p], tt = xpt[2 * p + 1];
                const float za = fmaf(x, w01.x, fmaf(tt, w11.x, bb.x));
                const float zb = fmaf(x, w01.y, fmaf(tt, w11.y, bb.y));
                const float ya = fast_tanh(za), yb = fast_tanh(zb);
                const float da = 1.f - ya * ya, db = 1.f - yb * yb;
                Hh[(0 * 16 + p) * HR + cp] = pkf16(ya, yb);
                Hh[(1 * 16 + p) * HR + cp] = pkf16(da * w01.x, db * w01.y);
                Hh[(2 * 16 + p) * HR + cp] = pkf16(da * w11.x, db * w11.y);
                Hh[(3 * 16 + p) * HR + cp] =
                    pkf16(-2.f * ya * da * w01.x * w01.x,
                          -2.f * yb * db * w01.y * w01.y);
            }
        } else {
            const int p0 = (tid >> 6) * 16;
            #pragma unroll
            for (int i = 0; i < 16; ++i) {
                const int p = p0 + i;
                const float x = xpt[2 * p], tt = xpt[2 * p + 1];
                const float za = fmaf(x, w01.x, fmaf(tt, w11.x, bb.x));
                const float zb = fmaf(x, w01.y, fmaf(tt, w11.y, bb.y));
                Hh[p * HR + cp] = pkf16(fast_tanh(za), fast_tanh(zb));
            }
        }
    }
    __syncthreads();

    // B-fragment pointers (coalesced: lane*8 within each 512-elem fragment).
    const _Float16* pb0h = wcf + (wv * 2 + 0) * 4096 + lane * 8;
    const _Float16* pb0l = pb0h + 2048;
    const _Float16* pb1h = wcf + (wv * 2 + 1) * 4096 + lane * 8;
    const _Float16* pb1l = pb1h + 2048;
    const float2* bh2 = (const float2*)bhid + (wv * 16 + lm);
    const int wc = wv * 16 + lm;   // epilogue dword column

    if (!isv) {
        // ================= derivative path =================
        for (int l = 0; l < 7; ++l) {
            f32x4 acc[4][2];
            #pragma unroll
            for (int s = 0; s < 4; ++s)
                #pragma unroll
                for (int j = 0; j < 2; ++j) acc[s][j] = (f32x4){0.f, 0.f, 0.f, 0.f};

            #pragma unroll
            for (int ks = 0; ks < 4; ++ks) {
                const int ro = ks * 16 + lq * 4;
                const f16x8 ah0 = *(const f16x8*)&Hh[(0 * 16 + lm) * HR + ro];
                const f16x8 ah1 = *(const f16x8*)&Hh[(1 * 16 + lm) * HR + ro];
                const f16x8 ah2 = *(const f16x8*)&Hh[(2 * 16 + lm) * HR + ro];
                const f16x8 ah3 = *(const f16x8*)&Hh[(3 * 16 + lm) * HR + ro];
                const f16x8 bh0 = *(const f16x8*)(pb0h + ks * 512);
                const f16x8 bl0 = *(const f16x8*)(pb0l + ks * 512);
                const f16x8 bh1 = *(const f16x8*)(pb1h + ks * 512);
                const f16x8 bl1 = *(const f16x8*)(pb1l + ks * 512);
                acc[0][0] = MFMA(ah0, bh0, acc[0][0]);
                acc[0][0] = MFMA(ah0, bl0, acc[0][0]);
                acc[1][0] = MFMA(ah1, bh0, acc[1][0]);
                acc[1][0] = MFMA(ah1, bl0, acc[1][0]);
                acc[2][0] = MFMA(ah2, bh0, acc[2][0]);
                acc[2][0] = MFMA(ah2, bl0, acc[2][0]);
                acc[3][0] = MFMA(ah3, bh0, acc[3][0]);
                acc[3][0] = MFMA(ah3, bl0, acc[3][0]);
                acc[0][1] = MFMA(ah0, bh1, acc[0][1]);
                acc[0][1] = MFMA(ah0, bl1, acc[0][1]);
                acc[1][1] = MFMA(ah1, bh1, acc[1][1]);
                acc[1][1] = MFMA(ah1, bl1, acc[1][1]);
                acc[2][1] = MFMA(ah2, bh1, acc[2][1]);
                acc[2][1] = MFMA(ah2, bl1, acc[2][1]);
                acc[3][1] = MFMA(ah3, bh1, acc[3][1]);
                acc[3][1] = MFMA(ah3, bl1, acc[3][1]);
            }
            __syncthreads();

            const float2 bb = bh2[l * 64];
            #pragma unroll
            for (int r = 0; r < 4; ++r) {
                const int p = lq * 4 + r;
                float h[2][4];
                #pragma unroll
                for (int j = 0; j < 2; ++j) {
                    const float zv  = acc[0][j][r] + (j ? bb.y : bb.x);
                    const float zx  = acc[1][j][r];
                    const float zt  = acc[2][j][r];
                    const float zxx = acc[3][j][r];
                    const float y = fast_tanh(zv);
                    const float d = fmaf(-y, y, 1.f);
                    const float m = d * zx;            // = h1
                    h[j][0] = y;
                    h[j][1] = m;
                    h[j][2] = d * zt;
                    h[j][3] = fmaf(d, zxx, -2.f * (y * m) * zx);
                }
                Hh[(0 * 16 + p) * HR + wc] = pkf16(h[0][0], h[1][0]);
                Hh[(1 * 16 + p) * HR + wc] = pkf16(h[0][1], h[1][1]);
                Hh[(2 * 16 + p) * HR + wc] = pkf16(h[0][2], h[1][2]);
                Hh[(3 * 16 + p) * HR + wc] = pkf16(h[0][3], h[1][3]);
            }
            pb0h += 32768; pb0l += 32768; pb1h += 32768; pb1l += 32768;
            __syncthreads();
        }
    } else {
        // ================= value-only path =================
        for (int l = 0; l < 7; ++l) {
            f32x4 acc[4][2];
            #pragma unroll
            for (int mt = 0; mt < 4; ++mt)
                #pragma unroll
                for (int j = 0; j < 2; ++j) acc[mt][j] = (f32x4){0.f, 0.f, 0.f, 0.f};

            #pragma unroll
            for (int ks = 0; ks < 4; ++ks) {
                const int ro = ks * 16 + lq * 4;
                f16x8 ah[4];
                #pragma unroll
                for (int mt = 0; mt < 4; ++mt)
                    ah[mt] = *(const f16x8*)&Hh[(mt * 16 + lm) * HR + ro];
                const f16x8 bh0 = *(const f16x8*)(pb0h + ks * 512);
                const f16x8 bl0 = *(const f16x8*)(pb0l + ks * 512);
                const f16x8 bh1 = *(const f16x8*)(pb1h + ks * 512);
                const f16x8 bl1 = *(const f16x8*)(pb1l + ks * 512);
                #pragma unroll
                for (int mt = 0; mt < 4; ++mt) {
                    acc[mt][0] = MFMA(ah[mt], bh0, acc[mt][0]);
                    acc[mt][0] = MFMA(ah[mt], bl0, acc[mt][0]);
                    acc[mt][1] = MFMA(ah[mt], bh1, acc[mt][1]);
                    acc[mt][1] = MFMA(ah[mt], bl1, acc[mt][1]);
                }
            }
            __syncthreads();

            const float2 bb = bh2[l * 64];
            #pragma unroll
            for (int mt = 0; mt < 4; ++mt) {
                #pragma unroll
                for (int r = 0; r < 4; ++r) {
                    const int p = mt * 16 + lq * 4 + r;
                    Hh[p * HR + wc] = pkf16(fast_tanh(acc[mt][0][r] + bb.x),
                                            fast_tanh(acc[mt][1][r] + bb.y));
                }
            }
            pb0h += 32768; pb0l += 32768; pb1h += 32768; pb1l += 32768;
            __syncthreads();
        }
    }

    // ---- output layer: 64 dots of length 128 ----
    {
        const int st = tid & 63;
        const int ch = tid >> 6;      // 16 dwords (32 channels) per chunk
        const int cb = ch * 16;
        float part = 0.f;
        #pragma unroll
        for (int c8 = 0; c8 < 4; ++c8) {
            const f16x8 hv = *(const f16x8*)&Hh[st * HR + cb + c8 * 4];
            const float4 w1 = *(const float4*)&Wout[cb * 2 + c8 * 8];
            const float4 w2 = *(const float4*)&Wout[cb * 2 + c8 * 8 + 4];
            part = fmaf((float)hv[0], w1.x, part);
            part = fmaf((float)hv[1], w1.y, part);
            part = fmaf((float)hv[2], w1.z, part);
            part = fmaf((float)hv[3], w1.w, part);
            part = fmaf((float)hv[4], w2.x, part);
            part = fmaf((float)hv[5], w2.y, part);
            part = fmaf((float)hv[6], w2.z, part);
            part = fmaf((float)hv[7], w2.w, part);
        }
        pbuf[ch * 64 + st] = part;
    }
    __syncthreads();
    if (tid < 64)
        dots[tid] = pbuf[tid] + pbuf[64 + tid] + pbuf[128 + tid] + pbuf[192 + tid];
    __syncthreads();
    if (!isv) {
        if (tid < 16) {
            const float u = dots[tid] + bout[0];
            out[8192 + blk * 16 + tid] =
                dots[32 + tid] + u * dots[16 + tid] - NU_F * dots[48 + tid];
        }
    } else {
        if (tid < 64) out[(blk - 8192) * 64 + tid] = dots[tid] + bout[0];
    }
}

extern "C" void kernel_launch(void* const* d_in, const int* in_sizes, int n_in,
                              void* d_out, int out_size, void* d_ws, size_t ws_size,
                              hipStream_t stream) {
    (void)in_sizes; (void)n_in; (void)ws_size; (void)out_size;
    const float* xf   = (const float*)d_in[0];
    const float* x0   = (const float*)d_in[1];
    const float* xbl  = (const float*)d_in[2];
    const float* xbr  = (const float*)d_in[3];
    const float* Win  = (const float*)d_in[4];
    const float* bin  = (const float*)d_in[5];
    const float* Whid = (const float*)d_in[6];
    const float* bhid = (const float*)d_in[7];
    const float* Wout = (const float*)d_in[8];
    const float* bout = (const float*)d_in[9];
    float* out = (float*)d_out;

    _Float16* wcf = (_Float16*)d_ws;   // 7*128*128*2 f16 = 448 KiB

    hipLaunchKernelGGL(prep_wfrag, dim3(114688 / 256), dim3(256), 0, stream,
                       Whid, wcf);
    hipLaunchKernelGGL(pinn_fused, dim3(8192 + 128), dim3(256), 0, stream,
                       xf, x0, xbl, xbr, Win, bin, bhid, Wout, bout, wcf, out);
}

// Round 10
// 227.779 us; speedup vs baseline: 2.6446x; 1.2859x over previous
//
#include <hip/hip_runtime.h>
#include <math.h>

#define NU_F 0.0031830988618379067f

typedef _Float16 f16x8 __attribute__((ext_vector_type(8)));
typedef float    f32x4 __attribute__((ext_vector_type(4)));

// tanh(z) = 1 - 2/(exp2(z*2log2e)+1); 5 VALU (2 transcendental)
__device__ __forceinline__ float fast_tanh(float z) {
    float e = __builtin_amdgcn_exp2f(2.885390082f * z);
    float r = __builtin_amdgcn_rcpf(e + 1.0f);
    return fmaf(-2.0f, r, 1.0f);
}

// pack two f32 -> f16x2 in one u32 (v_cvt_pkrtz_f32_f16), low16 = a
__device__ __forceinline__ unsigned pkf16(float a, float b) {
    auto v = __builtin_amdgcn_cvt_pkrtz(a, b);   // __fp16 ext_vector(2)
    return __builtin_bit_cast(unsigned, v);
}

// ---------------------------------------------------------------------------
// Prep: W_hid fp32 [7][128(k)][128(c)] -> SINGLE f16 (RNE) B-fragments,
// fragment-major (each wave-load = one coalesced 1 KiB block):
//   fid = (l*8 + nt)*4 + ks ; element = fid*512 + lane*8 + jj
//   k = ks*32 + q*8 + jj, lane = q*16 + nn
//   channel map: nt = ((c>>5)<<1)|(c&1), nn = (c>>1)&15  ->  c = wv*32+nn*2+j
// W-lo term dropped: A operand is already RTZ f16 (rel err 2^-10, biased)
// with no visible absmax change; W RNE rel err 2^-11 is strictly smaller.
// ---------------------------------------------------------------------------
__global__ void prep_wfrag(const float* __restrict__ Whid, _Float16* __restrict__ wcf)
{
    int t = blockIdx.x * 256 + threadIdx.x;   // 0 .. 114687
    const int l = t >> 14;
    const int r = t & 16383;
    const int k = r >> 7;
    const int c = r & 127;
    const _Float16 hi = (_Float16)Whid[t];
    const int ks = k >> 5, q = (k >> 3) & 3, jj = k & 7;
    const int nt = ((c >> 5) << 1) | (c & 1);
    const int nn = (c >> 1) & 15;
    const int lane = q * 16 + nn;
    wcf[((l * 8 + nt) * 4 + ks) * 512 + lane * 8 + jj] = hi;
}

#define HR 68
#define MFMA(A, B, C) __builtin_amdgcn_mfma_f32_16x16x32_f16((A), (B), (C), 0, 0, 0)

// ---------------------------------------------------------------------------
// Fused kernel, 256 thr = 4 waves, wave -> N-tiles {2wv, 2wv+1}.
// Blocks 0..8191: 16 deriv pts; M rows = s*16+p (jet states v,vx,vt,vxx).
// Blocks 8192..8319: 64 value-only pts; M rows = p.
// H: DOUBLE-BUFFERED f16 arrays (u32-packed channel pairs), 2 x 64 x 68.
// Layer l reads Hh[l&1], writes Hh[(l+1)&1] -> ONE barrier per layer
// (reads/writes hit disjoint buffers, so no K-loop/epilogue barrier).
// __launch_bounds__(256,5): 102-reg budget -- (256,8)'s 64-reg cap caused
// a scratch-spill storm (round 8).
// ---------------------------------------------------------------------------
__global__ __launch_bounds__(256, 5)
void pinn_fused(const float* __restrict__ xf,
                const float* __restrict__ x0,  const float* __restrict__ xbl,
                const float* __restrict__ xbr,
                const float* __restrict__ Win,  const float* __restrict__ bin,
                const float* __restrict__ bhid,
                const float* __restrict__ Wout, const float* __restrict__ bout,
                const _Float16* __restrict__ wcf,
                float* __restrict__ out)
{
    __shared__ unsigned Hh[2][64 * HR];
    __shared__ float xpt[128];
    __shared__ float pbuf[256];
    __shared__ float dots[64];

    const int tid  = threadIdx.x;
    const int lane = tid & 63;
    const int wv   = tid >> 6;
    const int lm   = lane & 15;
    const int lq   = lane >> 4;
    const int blk  = blockIdx.x;
    const bool isv = (blk >= 8192);

    if (!isv) {
        if (tid < 32) xpt[tid] = xf[blk * 32 + tid];
    } else {
        const int vb = blk - 8192;
        const float* src = (vb < 64) ? (x0 + vb * 128)
                         : (vb < 96) ? (xbl + (vb - 64) * 128)
                                     : (xbr + (vb - 96) * 128);
        if (tid < 128) xpt[tid] = src[tid];
    }
    __syncthreads();

    // ---- input layer: thread owns channel pair c0=2*(tid&63); writes buf 0 ----
    const int cp = tid & 63;
    {
        const float2 w01 = *(const float2*)&Win[cp * 2];
        const float2 w11 = *(const float2*)&Win[128 + cp * 2];
        const float2 bb  = *(const float2*)&bin[cp * 2];
        if (!isv) {
            const int p0 = (tid >> 6) * 4;
            #pragma unroll
            for (int i = 0; i < 4; ++i) {
                const int p = p0 + i;
                const float x = xpt[2 * p], tt = xpt[2 * p + 1];
                const float za = fmaf(x, w01.x, fmaf(tt, w11.x, bb.x));
                const float zb = fmaf(x, w01.y, fmaf(tt, w11.y, bb.y));
                const float ya = fast_tanh(za), yb = fast_tanh(zb);
                const float da = 1.f - ya * ya, db = 1.f - yb * yb;
                Hh[0][(0 * 16 + p) * HR + cp] = pkf16(ya, yb);
                Hh[0][(1 * 16 + p) * HR + cp] = pkf16(da * w01.x, db * w01.y);
                Hh[0][(2 * 16 + p) * HR + cp] = pkf16(da * w11.x, db * w11.y);
                Hh[0][(3 * 16 + p) * HR + cp] =
                    pkf16(-2.f * ya * da * w01.x * w01.x,
                          -2.f * yb * db * w01.y * w01.y);
            }
        } else {
            const int p0 = (tid >> 6) * 16;
            #pragma unroll
            for (int i = 0; i < 16; ++i) {
                const int p = p0 + i;
                const float x = xpt[2 * p], tt = xpt[2 * p + 1];
                const float za = fmaf(x, w01.x, fmaf(tt, w11.x, bb.x));
                const float zb = fmaf(x, w01.y, fmaf(tt, w11.y, bb.y));
                Hh[0][p * HR + cp] = pkf16(fast_tanh(za), fast_tanh(zb));
            }
        }
    }
    __syncthreads();

    // B-fragment pointers (coalesced: lane*8 within each 512-elem fragment).
    // nt stride = 2048 elem, ks stride = 512 elem, layer stride = 16384 elem.
    const _Float16* pb0 = wcf + (wv * 2 + 0) * 2048 + lane * 8;
    const _Float16* pb1 = wcf + (wv * 2 + 1) * 2048 + lane * 8;
    const float2* bh2 = (const float2*)bhid + (wv * 16 + lm);
    const int wc = wv * 16 + lm;   // epilogue dword column

    if (!isv) {
        // ================= derivative path =================
        for (int l = 0; l < 7; ++l) {
            const unsigned* Hc = Hh[l & 1];
            unsigned*       Hn = Hh[(l + 1) & 1];
            f32x4 acc[4][2];
            #pragma unroll
            for (int s = 0; s < 4; ++s)
                #pragma unroll
                for (int j = 0; j < 2; ++j) acc[s][j] = (f32x4){0.f, 0.f, 0.f, 0.f};

            #pragma unroll
            for (int ks = 0; ks < 4; ++ks) {
                const int ro = ks * 16 + lq * 4;
                const f16x8 ah0 = *(const f16x8*)&Hc[(0 * 16 + lm) * HR + ro];
                const f16x8 ah1 = *(const f16x8*)&Hc[(1 * 16 + lm) * HR + ro];
                const f16x8 ah2 = *(const f16x8*)&Hc[(2 * 16 + lm) * HR + ro];
                const f16x8 ah3 = *(const f16x8*)&Hc[(3 * 16 + lm) * HR + ro];
                const f16x8 bh0 = *(const f16x8*)(pb0 + ks * 512);
                const f16x8 bh1 = *(const f16x8*)(pb1 + ks * 512);
                acc[0][0] = MFMA(ah0, bh0, acc[0][0]);
                acc[1][0] = MFMA(ah1, bh0, acc[1][0]);
                acc[2][0] = MFMA(ah2, bh0, acc[2][0]);
                acc[3][0] = MFMA(ah3, bh0, acc[3][0]);
                acc[0][1] = MFMA(ah0, bh1, acc[0][1]);
                acc[1][1] = MFMA(ah1, bh1, acc[1][1]);
                acc[2][1] = MFMA(ah2, bh1, acc[2][1]);
                acc[3][1] = MFMA(ah3, bh1, acc[3][1]);
            }

            const float2 bb = bh2[l * 64];
            #pragma unroll
            for (int r = 0; r < 4; ++r) {
                const int p = lq * 4 + r;
                float h[2][4];
                #pragma unroll
                for (int j = 0; j < 2; ++j) {
                    const float zv  = acc[0][j][r] + (j ? bb.y : bb.x);
                    const float zx  = acc[1][j][r];
                    const float zt  = acc[2][j][r];
                    const float zxx = acc[3][j][r];
                    const float y = fast_tanh(zv);
                    const float d = fmaf(-y, y, 1.f);
                    const float m = d * zx;            // = h1
                    h[j][0] = y;
                    h[j][1] = m;
                    h[j][2] = d * zt;
                    h[j][3] = fmaf(d, zxx, -2.f * (y * m) * zx);
                }
                Hn[(0 * 16 + p) * HR + wc] = pkf16(h[0][0], h[1][0]);
                Hn[(1 * 16 + p) * HR + wc] = pkf16(h[0][1], h[1][1]);
                Hn[(2 * 16 + p) * HR + wc] = pkf16(h[0][2], h[1][2]);
                Hn[(3 * 16 + p) * HR + wc] = pkf16(h[0][3], h[1][3]);
            }
            pb0 += 16384; pb1 += 16384;
            __syncthreads();   // next layer's reads follow this wave's writes
        }
    } else {
        // ================= value-only path =================
        for (int l = 0; l < 7; ++l) {
            const unsigned* Hc = Hh[l & 1];
            unsigned*       Hn = Hh[(l + 1) & 1];
            f32x4 acc[4][2];
            #pragma unroll
            for (int mt = 0; mt < 4; ++mt)
                #pragma unroll
                for (int j = 0; j < 2; ++j) acc[mt][j] = (f32x4){0.f, 0.f, 0.f, 0.f};

            #pragma unroll
            for (int ks = 0; ks < 4; ++ks) {
                const int ro = ks * 16 + lq * 4;
                f16x8 ah[4];
                #pragma unroll
                for (int mt = 0; mt < 4; ++mt)
                    ah[mt] = *(const f16x8*)&Hc[(mt * 16 + lm) * HR + ro];
                const f16x8 bh0 = *(const f16x8*)(pb0 + ks * 512);
                const f16x8 bh1 = *(const f16x8*)(pb1 + ks * 512);
                #pragma unroll
                for (int mt = 0; mt < 4; ++mt) {
                    acc[mt][0] = MFMA(ah[mt], bh0, acc[mt][0]);
                    acc[mt][1] = MFMA(ah[mt], bh1, acc[mt][1]);
                }
            }

            const float2 bb = bh2[l * 64];
            #pragma unroll
            for (int mt = 0; mt < 4; ++mt) {
                #pragma unroll
                for (int r = 0; r < 4; ++r) {
                    const int p = mt * 16 + lq * 4 + r;
                    Hn[p * HR + wc] = pkf16(fast_tanh(acc[mt][0][r] + bb.x),
                                            fast_tanh(acc[mt][1][r] + bb.y));
                }
            }
            pb0 += 16384; pb1 += 16384;
            __syncthreads();
        }
    }

    // ---- output layer: 64 dots of length 128 (final H in buf 1) ----
    {
        const unsigned* Hf = Hh[1];
        const int st = tid & 63;
        const int ch = tid >> 6;      // 16 dwords (32 channels) per chunk
        const int cb = ch * 16;
        float part = 0.f;
        #pragma unroll
        for (int c8 = 0; c8 < 4; ++c8) {
            const f16x8 hv = *(const f16x8*)&Hf[st * HR + cb + c8 * 4];
            const float4 w1 = *(const float4*)&Wout[cb * 2 + c8 * 8];
            const float4 w2 = *(const float4*)&Wout[cb * 2 + c8 * 8 + 4];
            part = fmaf((float)hv[0], w1.x, part);
            part = fmaf((float)hv[1], w1.y, part);
            part = fmaf((float)hv[2], w1.z, part);
            part = fmaf((float)hv[3], w1.w, part);
            part = fmaf((float)hv[4], w2.x, part);
            part = fmaf((float)hv[5], w2.y, part);
            part = fmaf((float)hv[6], w2.z, part);
            part = fmaf((float)hv[7], w2.w, part);
        }
        pbuf[ch * 64 + st] = part;
    }
    __syncthreads();
    if (tid < 64)
        dots[tid] = pbuf[tid] + pbuf[64 + tid] + pbuf[128 + tid] + pbuf[192 + tid];
    __syncthreads();
    if (!isv) {
        if (tid < 16) {
            const float u = dots[tid] + bout[0];
            out[8192 + blk * 16 + tid] =
                dots[32 + tid] + u * dots[16 + tid] - NU_F * dots[48 + tid];
        }
    } else {
        if (tid < 64) out[(blk - 8192) * 64 + tid] = dots[tid] + bout[0];
    }
}

extern "C" void kernel_launch(void* const* d_in, const int* in_sizes, int n_in,
                              void* d_out, int out_size, void* d_ws, size_t ws_size,
                              hipStream_t stream) {
    (void)in_sizes; (void)n_in; (void)ws_size; (void)out_size;
    const float* xf   = (const float*)d_in[0];
    const float* x0   = (const float*)d_in[1];
    const float* xbl  = (const float*)d_in[2];
    const float* xbr  = (const float*)d_in[3];
    const float* Win  = (const float*)d_in[4];
    const float* bin  = (const float*)d_in[5];
    const float* Whid = (const float*)d_in[6];
    const float* bhid = (const float*)d_in[7];
    const float* Wout = (const float*)d_in[8];
    const float* bout = (const float*)d_in[9];
    float* out = (float*)d_out;

    _Float16* wcf = (_Float16*)d_ws;   // 7*128*128 f16 = 224 KiB

    hipLaunchKernelGGL(prep_wfrag, dim3(114688 / 256), dim3(256), 0, stream,
                       Whid, wcf);
    hipLaunchKernelGGL(pinn_fused, dim3(8192 + 128), dim3(256), 0, stream,
                       xf, x0, xbl, xbr, Win, bin, bhid, Wout, bout, wcf, out);
}